// Round 6
// baseline (1071.809 us; speedup 1.0000x reference)
//
#include <hip/hip_runtime.h>
#include <stdint.h>

#define TT 128
#define BSZ 512
#define HID 512
#define KDIM 512
#define BH (BSZ*HID)   // 262144 neurons

// ---------------- fp32 tiled GEMM: C[m][n] = sum_k A[m][k] * W[n][k] + bias[n] --------
// v7 = v5 structure (32 VGPR acc, B-only-ish LDS, 4 blocks/CU) + A through LDS.
// Evidence trail: v5 (wave-uniform A via s_load) = 437us @ 61% VALUBusy. Conflict audit:
// v5's 16.78M conflict-cycles / 8.4M b128 reads = ~2 cyc/read extra -> B-path was fine.
// The idle was the A-path: uniform float4 A loads compile to s_load_dwordx4, which
// shares lgkmcnt with ds_read and returns OUT OF ORDER -> conservative lgkmcnt(0)
// waits drain the whole ds_read pipeline once per kq (4x per k-tile). v6 (b32 B reads)
// regressed (712us total): 4x LDS instruction count, pure issue/wait inflation.
// Fix: A staged into a tiny LDS tile (32m x 16k = 2KB x2buf, staged as float2/thread,
// 2-way-free writes), read per-kk as wave-uniform ds_read_b128 (same-address broadcast,
// conflict-free, IN-ORDER with B ds_reads -> compiler's fine-grained lgkmcnt(N)
// pipelining works; no scalar-cache / vmcnt stall in the loop).
// Block: 256 thr = 4 waves; tile 32(m) x 256(n); wave = 8m x 256n; BK=16; dbuf;
// one barrier per k-tile. LDS 37888B -> 4 blocks/CU.
// NUMERICS CONTRACT (bit-exact vs np ref, absmax 0.0): per output element the
// reduction is ONE sequential fp32 fma chain over k ascending, in one lane. Unchanged.
__global__ __launch_bounds__(256, 4) void gemm_f32(
    const float* __restrict__ A, const float* __restrict__ W,
    const float* __restrict__ bias, float* __restrict__ C) {
  __shared__ float As[2][16][36];    // [buf][k][m], +4 pad; row stride 144B (16B-mult)
  __shared__ float Bs[2][16][260];   // [buf][k][n], +4 pad (proven pattern)
  const int t    = threadIdx.x;
  const int m0   = blockIdx.y * 32;
  const int n0   = blockIdx.x * 256;
  const int lane = t & 63;
  const int wid  = t >> 6;           // 0..3 (uniform per wave)
  const int r0   = t >> 2;           // B staging row 0..63 (+64/128/192 replicas)
  const int kg   = t & 3;            // B staging k-group
  const int ar   = t >> 3;           // A staging row 0..31
  const int ak   = (t & 7) * 2;      // A staging k: 0,2,..,14

  float acc[8][4];                   // acc[i][j] -> C[m0+wid*8+i][n0 + lane*4 + j]
  #pragma unroll
  for (int i = 0; i < 8; ++i)
    #pragma unroll
    for (int j = 0; j < 4; ++j) acc[i][j] = 0.f;

  const float* Wp  = W + (size_t)(n0 + r0) * KDIM + kg * 4;
  const float* Apg = A + (size_t)(m0 + ar) * KDIM + ak;

  float4 w0 = *(const float4*)Wp;
  float4 w1 = *(const float4*)(Wp + (size_t)64  * KDIM);
  float4 w2 = *(const float4*)(Wp + (size_t)128 * KDIM);
  float4 w3 = *(const float4*)(Wp + (size_t)192 * KDIM);
  float2 a01 = *(const float2*)Apg;

  // stage tiles into buffer BUF. B: 16 b32 scatter writes, 2-way alias = free (proven).
  // A: 2 b32 writes/thread, bank (4*ak + ar) & (4*(ak+1) + ar) patterns = 2-way = free.
  #define STAGE(BUF) do { \
    Bs[BUF][kg*4+0][r0]     = w0.x; Bs[BUF][kg*4+1][r0]     = w0.y; \
    Bs[BUF][kg*4+2][r0]     = w0.z; Bs[BUF][kg*4+3][r0]     = w0.w; \
    Bs[BUF][kg*4+0][r0+64]  = w1.x; Bs[BUF][kg*4+1][r0+64]  = w1.y; \
    Bs[BUF][kg*4+2][r0+64]  = w1.z; Bs[BUF][kg*4+3][r0+64]  = w1.w; \
    Bs[BUF][kg*4+0][r0+128] = w2.x; Bs[BUF][kg*4+1][r0+128] = w2.y; \
    Bs[BUF][kg*4+2][r0+128] = w2.z; Bs[BUF][kg*4+3][r0+128] = w2.w; \
    Bs[BUF][kg*4+0][r0+192] = w3.x; Bs[BUF][kg*4+1][r0+192] = w3.y; \
    Bs[BUF][kg*4+2][r0+192] = w3.z; Bs[BUF][kg*4+3][r0+192] = w3.w; \
    As[BUF][ak][ar]         = a01.x; \
    As[BUF][ak+1][ar]       = a01.y; \
  } while (0)

  STAGE(0);

  int cur = 0;
  for (int k0 = 0; k0 < KDIM; k0 += 16) {
    // Single barrier per tile (drains all mem ops): buf[cur] writes visible, and the
    // previous iteration's ds_reads of buf[cur^1] are complete -> restaging is safe.
    __syncthreads();
    const bool more = (k0 + 16 < KDIM);
    if (more) {   // vector prefetch of next tile; latency hidden under fma block
      w0  = *(const float4*)(Wp + k0 + 16);
      w1  = *(const float4*)(Wp + (size_t)64  * KDIM + k0 + 16);
      w2  = *(const float4*)(Wp + (size_t)128 * KDIM + k0 + 16);
      w3  = *(const float4*)(Wp + (size_t)192 * KDIM + k0 + 16);
      a01 = *(const float2*)(Apg + k0 + 16);
    }

    #pragma unroll
    for (int kk = 0; kk < 16; ++kk) {
      // A: wave-uniform ds_read_b128 x2 (same-address broadcast, conflict-free,
      // 16B-aligned: row stride 144B, col offset wid*32B).
      const float4 xa0 = *(const float4*)&As[cur][kk][wid*8];
      const float4 xa1 = *(const float4*)&As[cur][kk][wid*8 + 4];
      // B: contiguous float4 per lane (v5 shape; audited ~2 cyc/read extra only).
      const float4 xb  = *(const float4*)&Bs[cur][kk][lane*4];
      const float a[8] = {xa0.x,xa0.y,xa0.z,xa0.w,xa1.x,xa1.y,xa1.z,xa1.w};
      #pragma unroll
      for (int i = 0; i < 8; ++i) {
        acc[i][0] = __builtin_fmaf(a[i], xb.x, acc[i][0]);
        acc[i][1] = __builtin_fmaf(a[i], xb.y, acc[i][1]);
        acc[i][2] = __builtin_fmaf(a[i], xb.z, acc[i][2]);
        acc[i][3] = __builtin_fmaf(a[i], xb.w, acc[i][3]);
      }
    }

    if (more) {
      const int nb = cur ^ 1;
      STAGE(nb);      // overlaps other waves' compute; protected by next barrier
    }
    cur ^= 1;
  }
  #undef STAGE

  // epilogue: + bias (ref adds b once to xp — identical), coalesced float4 stores
  const float4 bv = *(const float4*)&bias[n0 + lane*4];
  #pragma unroll
  for (int i = 0; i < 8; ++i) {
    const float4 v = {acc[i][0] + bv.x, acc[i][1] + bv.y,
                      acc[i][2] + bv.z, acc[i][3] + bv.w};
    *(float4*)(C + (size_t)(m0 + wid*8 + i) * HID + n0 + lane*4) = v;
  }
}

// ---------------- LIF scan (bit-identical to np fp32 reference given xp) ----------------
__device__ __forceinline__ float lif_step(float y, float v[4], float av[4]) {
  float as3 = 0.f;
  #pragma unroll
  for (int l = 0; l < 4; ++l) {
    float vv = v[l];
    float accv = 0.f, accs = 0.f;
    #pragma unroll
    for (int k = 0; k < 4; ++k) {
      const float d = y - vv;                        // round(inp - v)
      vv = __builtin_fmaf(d, 0.5f, vv);              // round(v + d*0.5): d*0.5 exact
      const float spk = (vv >= 1.0f) ? 1.0f : 0.0f;  // v-1>=0 <=> v>=1 (exact)
      vv -= spk;                                     // soft reset
      accv += vv;
      accs += spk;
    }
    v[l] = vv;
    const float a = accv * 0.25f;                    // exact /4
    av[l] = a;
    y = a;                                           // next layer consumes avg_v
    as3 = accs;
  }
  return as3;
}

// One thread per neuron. xp loads are INDEPENDENT across t (precomputed array).
// 8-deep prefetch + nontemporal xp loads / out stores (each touched exactly once).
__global__ __launch_bounds__(256) void lif_scan(
    const float* __restrict__ xp, float* __restrict__ outp, float* __restrict__ vstate,
    int tc, int first, int last) {
  const int idx = blockIdx.x * 256 + threadIdx.x;
  float v[4];
  if (first) {
    #pragma unroll
    for (int l = 0; l < 4; ++l) v[l] = 0.f;
  } else {
    #pragma unroll
    for (int l = 0; l < 4; ++l) v[l] = vstate[(size_t)l * BH + idx];
  }
  float av[4] = {0.f, 0.f, 0.f, 0.f};
  const float* p = xp + idx;
  float* op = outp + idx;

  if ((tc & 7) == 0 && tc >= 16) {
    float curb[8];
    #pragma unroll
    for (int i = 0; i < 8; ++i) curb[i] = __builtin_nontemporal_load(&p[(size_t)i * BH]);
    for (int t = 0; t + 8 < tc; t += 8) {
      float nxtb[8];
      #pragma unroll
      for (int i = 0; i < 8; ++i)
        nxtb[i] = __builtin_nontemporal_load(&p[(size_t)(i + 8) * BH]);  // pre-compute
      #pragma unroll
      for (int i = 0; i < 8; ++i) {
        const float as3 = lif_step(curb[i], v, av);
        __builtin_nontemporal_store(as3 * 0.25f, &op[(size_t)i * BH]);
      }
      #pragma unroll
      for (int i = 0; i < 8; ++i) curb[i] = nxtb[i];
      p += 8 * BH; op += 8 * BH;
    }
    #pragma unroll
    for (int i = 0; i < 8; ++i) {    // tail group, already in registers
      const float as3 = lif_step(curb[i], v, av);
      __builtin_nontemporal_store(as3 * 0.25f, &op[(size_t)i * BH]);
    }
  } else {
    for (int t = 0; t < tc; ++t) {
      const float as3 = lif_step(p[0], v, av);
      *op = as3 * 0.25f;
      p += BH; op += BH;
    }
  }

  if (last) {
    #pragma unroll
    for (int l = 0; l < 4; ++l) vstate[(size_t)l * BH + idx] = av[l];
  } else {
    #pragma unroll
    for (int l = 0; l < 4; ++l) vstate[(size_t)l * BH + idx] = v[l];
  }
}

extern "C" void kernel_launch(void* const* d_in, const int* in_sizes, int n_in,
                              void* d_out, int out_size, void* d_ws, size_t ws_size,
                              hipStream_t stream) {
  const float* x = (const float*)d_in[0];   // [128,512,512] fp32
  const float* W = (const float*)d_in[1];   // [512,512] fp32
  const float* b = (const float*)d_in[2];   // [512] fp32
  float* out    = (float*)d_out;            // [128,512,512] avg spikes (fp32)
  float* states = out + (size_t)TT * BH;    // [4,512,512] final avg_v; also chunk-carry v

  int tc = TT;                              // xp chunk: tc MiB of ws
  while (tc > 1 && (size_t)tc * BH * 4ull > ws_size) tc >>= 1;
  float* xp = (float*)d_ws;
  const int nc = TT / tc;

  for (int c = 0; c < nc; ++c) {
    hipLaunchKernelGGL(gemm_f32, dim3(HID / 256, tc * BSZ / 32), dim3(256), 0, stream,
                       x + (size_t)c * tc * BH, W, b, xp);
    hipLaunchKernelGGL(lif_scan, dim3(BH / 256), dim3(256), 0, stream,
                       xp, out + (size_t)c * tc * BH, states,
                       tc, c == 0 ? 1 : 0, c == nc - 1 ? 1 : 0);
  }
}

// Round 7
// 668.022 us; speedup vs baseline: 1.6045x; 1.6045x over previous
//
#include <hip/hip_runtime.h>
#include <stdint.h>

#define TT 128
#define BSZ 512
#define HID 512
#define KDIM 512
#define BH (BSZ*HID)   // 262144 neurons

// ---------------- fp32 tiled GEMM: C[m][n] = sum_k A[m][k] * W[n][k] + bias[n] --------
// v8 = v7 with the spill fixed (ONE variable: __launch_bounds__ (256,4) -> (256,1)).
// v7 post-mortem: WRITE_SIZE 131MB -> 2.10GB, HBM 2.7TB/s, 911us — the allocator kept
// 64 arch VGPRs (8-wave/SIMD granule, per the (256,4) min-occupancy hint) against ~80
// of demand and spilled the prefetch registers held across the fma block (~2KB/thread
// of scratch traffic). With (256,1) the allocator is free (R2: picks <=128); demand ~80
// fits -> no spill, 4 waves/SIMD; LDS 37888B still gives 4 blocks/CU = 16 waves/CU.
// Structure (unchanged from v7, theory still under test): wave-uniform-A moved from
// s_load (v5: OUT-OF-ORDER scalar loads share lgkmcnt with ds_read -> conservative
// lgkmcnt(0) drains serialize the LDS pipe 4x/k-tile -> 39% idle) into a tiny LDS tile
// (32m x 16k x2buf), read per-kk as wave-uniform ds_read_b128 broadcast — IN-ORDER
// with B ds_reads so the compiler's fine-grained lgkmcnt(N) pipelining works.
// B path: v5's contiguous float4/lane (audited: ~2 cyc/read extra only — near-minimal
// for wave64 b128). Staging writes 2-way max = free. dbuf, one barrier per k-tile.
// Block: 256 thr = 4 waves; tile 32(m) x 256(n); wave = 8m x 256n; BK=16.
// NUMERICS CONTRACT (bit-exact vs np ref, absmax 0.0): per output element the
// reduction is ONE sequential fp32 fma chain over k ascending, in one lane. Unchanged.
__global__ __launch_bounds__(256, 1) void gemm_f32(
    const float* __restrict__ A, const float* __restrict__ W,
    const float* __restrict__ bias, float* __restrict__ C) {
  __shared__ float As[2][16][36];    // [buf][k][m], +4 pad; row stride 144B (16B-mult)
  __shared__ float Bs[2][16][260];   // [buf][k][n], +4 pad (proven pattern)
  const int t    = threadIdx.x;
  const int m0   = blockIdx.y * 32;
  const int n0   = blockIdx.x * 256;
  const int lane = t & 63;
  const int wid  = t >> 6;           // 0..3 (uniform per wave)
  const int r0   = t >> 2;           // B staging row 0..63 (+64/128/192 replicas)
  const int kg   = t & 3;            // B staging k-group
  const int ar   = t >> 3;           // A staging row 0..31
  const int ak   = (t & 7) * 2;      // A staging k: 0,2,..,14

  float acc[8][4];                   // acc[i][j] -> C[m0+wid*8+i][n0 + lane*4 + j]
  #pragma unroll
  for (int i = 0; i < 8; ++i)
    #pragma unroll
    for (int j = 0; j < 4; ++j) acc[i][j] = 0.f;

  const float* Wp  = W + (size_t)(n0 + r0) * KDIM + kg * 4;
  const float* Apg = A + (size_t)(m0 + ar) * KDIM + ak;

  float4 w0 = *(const float4*)Wp;
  float4 w1 = *(const float4*)(Wp + (size_t)64  * KDIM);
  float4 w2 = *(const float4*)(Wp + (size_t)128 * KDIM);
  float4 w3 = *(const float4*)(Wp + (size_t)192 * KDIM);
  float2 a01 = *(const float2*)Apg;

  // stage tiles into buffer BUF. B: 16 b32 scatter writes, 2-way alias = free (proven).
  // A: 2 b32 writes/thread, bank (4*ak + ar) patterns = 2-way = free.
  #define STAGE(BUF) do { \
    Bs[BUF][kg*4+0][r0]     = w0.x; Bs[BUF][kg*4+1][r0]     = w0.y; \
    Bs[BUF][kg*4+2][r0]     = w0.z; Bs[BUF][kg*4+3][r0]     = w0.w; \
    Bs[BUF][kg*4+0][r0+64]  = w1.x; Bs[BUF][kg*4+1][r0+64]  = w1.y; \
    Bs[BUF][kg*4+2][r0+64]  = w1.z; Bs[BUF][kg*4+3][r0+64]  = w1.w; \
    Bs[BUF][kg*4+0][r0+128] = w2.x; Bs[BUF][kg*4+1][r0+128] = w2.y; \
    Bs[BUF][kg*4+2][r0+128] = w2.z; Bs[BUF][kg*4+3][r0+128] = w2.w; \
    Bs[BUF][kg*4+0][r0+192] = w3.x; Bs[BUF][kg*4+1][r0+192] = w3.y; \
    Bs[BUF][kg*4+2][r0+192] = w3.z; Bs[BUF][kg*4+3][r0+192] = w3.w; \
    As[BUF][ak][ar]         = a01.x; \
    As[BUF][ak+1][ar]       = a01.y; \
  } while (0)

  STAGE(0);

  int cur = 0;
  for (int k0 = 0; k0 < KDIM; k0 += 16) {
    // Single barrier per tile (drains all mem ops): buf[cur] writes visible, and the
    // previous iteration's ds_reads of buf[cur^1] are complete -> restaging is safe.
    __syncthreads();
    const bool more = (k0 + 16 < KDIM);
    if (more) {   // vector prefetch of next tile; latency hidden under fma block
      w0  = *(const float4*)(Wp + k0 + 16);
      w1  = *(const float4*)(Wp + (size_t)64  * KDIM + k0 + 16);
      w2  = *(const float4*)(Wp + (size_t)128 * KDIM + k0 + 16);
      w3  = *(const float4*)(Wp + (size_t)192 * KDIM + k0 + 16);
      a01 = *(const float2*)(Apg + k0 + 16);
    }

    #pragma unroll
    for (int kk = 0; kk < 16; ++kk) {
      // A: wave-uniform ds_read_b128 x2 (same-address broadcast, conflict-free,
      // 16B-aligned: row stride 144B, col offset wid*32B).
      const float4 xa0 = *(const float4*)&As[cur][kk][wid*8];
      const float4 xa1 = *(const float4*)&As[cur][kk][wid*8 + 4];
      // B: contiguous float4 per lane (v5 shape; audited ~2 cyc/read extra only).
      const float4 xb  = *(const float4*)&Bs[cur][kk][lane*4];
      const float a[8] = {xa0.x,xa0.y,xa0.z,xa0.w,xa1.x,xa1.y,xa1.z,xa1.w};
      #pragma unroll
      for (int i = 0; i < 8; ++i) {
        acc[i][0] = __builtin_fmaf(a[i], xb.x, acc[i][0]);
        acc[i][1] = __builtin_fmaf(a[i], xb.y, acc[i][1]);
        acc[i][2] = __builtin_fmaf(a[i], xb.z, acc[i][2]);
        acc[i][3] = __builtin_fmaf(a[i], xb.w, acc[i][3]);
      }
    }

    if (more) {
      const int nb = cur ^ 1;
      STAGE(nb);      // overlaps other waves' compute; protected by next barrier
    }
    cur ^= 1;
  }
  #undef STAGE

  // epilogue: + bias (ref adds b once to xp — identical), coalesced float4 stores
  const float4 bv = *(const float4*)&bias[n0 + lane*4];
  #pragma unroll
  for (int i = 0; i < 8; ++i) {
    const float4 v = {acc[i][0] + bv.x, acc[i][1] + bv.y,
                      acc[i][2] + bv.z, acc[i][3] + bv.w};
    *(float4*)(C + (size_t)(m0 + wid*8 + i) * HID + n0 + lane*4) = v;
  }
}

// ---------------- LIF scan (bit-identical to np fp32 reference given xp) ----------------
__device__ __forceinline__ float lif_step(float y, float v[4], float av[4]) {
  float as3 = 0.f;
  #pragma unroll
  for (int l = 0; l < 4; ++l) {
    float vv = v[l];
    float accv = 0.f, accs = 0.f;
    #pragma unroll
    for (int k = 0; k < 4; ++k) {
      const float d = y - vv;                        // round(inp - v)
      vv = __builtin_fmaf(d, 0.5f, vv);              // round(v + d*0.5): d*0.5 exact
      const float spk = (vv >= 1.0f) ? 1.0f : 0.0f;  // v-1>=0 <=> v>=1 (exact)
      vv -= spk;                                     // soft reset
      accv += vv;
      accs += spk;
    }
    v[l] = vv;
    const float a = accv * 0.25f;                    // exact /4
    av[l] = a;
    y = a;                                           // next layer consumes avg_v
    as3 = accs;
  }
  return as3;
}

// One thread per neuron. xp loads are INDEPENDENT across t (precomputed array).
// 8-deep prefetch + nontemporal xp loads / out stores (each touched exactly once).
__global__ __launch_bounds__(256) void lif_scan(
    const float* __restrict__ xp, float* __restrict__ outp, float* __restrict__ vstate,
    int tc, int first, int last) {
  const int idx = blockIdx.x * 256 + threadIdx.x;
  float v[4];
  if (first) {
    #pragma unroll
    for (int l = 0; l < 4; ++l) v[l] = 0.f;
  } else {
    #pragma unroll
    for (int l = 0; l < 4; ++l) v[l] = vstate[(size_t)l * BH + idx];
  }
  float av[4] = {0.f, 0.f, 0.f, 0.f};
  const float* p = xp + idx;
  float* op = outp + idx;

  if ((tc & 7) == 0 && tc >= 16) {
    float curb[8];
    #pragma unroll
    for (int i = 0; i < 8; ++i) curb[i] = __builtin_nontemporal_load(&p[(size_t)i * BH]);
    for (int t = 0; t + 8 < tc; t += 8) {
      float nxtb[8];
      #pragma unroll
      for (int i = 0; i < 8; ++i)
        nxtb[i] = __builtin_nontemporal_load(&p[(size_t)(i + 8) * BH]);  // pre-compute
      #pragma unroll
      for (int i = 0; i < 8; ++i) {
        const float as3 = lif_step(curb[i], v, av);
        __builtin_nontemporal_store(as3 * 0.25f, &op[(size_t)i * BH]);
      }
      #pragma unroll
      for (int i = 0; i < 8; ++i) curb[i] = nxtb[i];
      p += 8 * BH; op += 8 * BH;
    }
    #pragma unroll
    for (int i = 0; i < 8; ++i) {    // tail group, already in registers
      const float as3 = lif_step(curb[i], v, av);
      __builtin_nontemporal_store(as3 * 0.25f, &op[(size_t)i * BH]);
    }
  } else {
    for (int t = 0; t < tc; ++t) {
      const float as3 = lif_step(p[0], v, av);
      *op = as3 * 0.25f;
      p += BH; op += BH;
    }
  }

  if (last) {
    #pragma unroll
    for (int l = 0; l < 4; ++l) vstate[(size_t)l * BH + idx] = av[l];
  } else {
    #pragma unroll
    for (int l = 0; l < 4; ++l) vstate[(size_t)l * BH + idx] = v[l];
  }
}

extern "C" void kernel_launch(void* const* d_in, const int* in_sizes, int n_in,
                              void* d_out, int out_size, void* d_ws, size_t ws_size,
                              hipStream_t stream) {
  const float* x = (const float*)d_in[0];   // [128,512,512] fp32
  const float* W = (const float*)d_in[1];   // [512,512] fp32
  const float* b = (const float*)d_in[2];   // [512] fp32
  float* out    = (float*)d_out;            // [128,512,512] avg spikes (fp32)
  float* states = out + (size_t)TT * BH;    // [4,512,512] final avg_v; also chunk-carry v

  int tc = TT;                              // xp chunk: tc MiB of ws
  while (tc > 1 && (size_t)tc * BH * 4ull > ws_size) tc >>= 1;
  float* xp = (float*)d_ws;
  const int nc = TT / tc;

  for (int c = 0; c < nc; ++c) {
    hipLaunchKernelGGL(gemm_f32, dim3(HID / 256, tc * BSZ / 32), dim3(256), 0, stream,
                       x + (size_t)c * tc * BH, W, b, xp);
    hipLaunchKernelGGL(lif_scan, dim3(BH / 256), dim3(256), 0, stream,
                       xp, out + (size_t)c * tc * BH, states,
                       tc, c == 0 ? 1 : 0, c == nc - 1 ? 1 : 0);
  }
}